// Round 7
// baseline (1057.598 us; speedup 1.0000x reference)
//
#include <hip/hip_runtime.h>
#include <hip/hip_bf16.h>

#define N_NODES 8192
#define FIN 512
#define FOUT 64
#define LRELU_ALPHA 0.2f

typedef __attribute__((ext_vector_type(8))) short short8;
typedef __attribute__((ext_vector_type(4))) float floatx4;

static __device__ __forceinline__ short f2bf_bits(float x) {
    union { __hip_bfloat16 b; short s; } u; u.b = __float2bfloat16(x); return u.s;
}

// ---------------------------------------------------------------------------
// Kernel 0: adj (int32 0/1, 256 MB) -> bitmask (8 MB). Pure streaming.
__global__ __launch_bounds__(256) void adj_bits(
    const int* __restrict__ adj, unsigned long long* __restrict__ bits)
{
    const int lane = threadIdx.x & 63;
    const int wid = blockIdx.x * 4 + (threadIdx.x >> 6);
    const size_t base = (size_t)wid * 128;
    const int* src = adj + base * 64 + lane;
    #pragma unroll 8
    for (int t = 0; t < 128; ++t) {
        int v = src[t * 64];
        unsigned long long m = __ballot(v > 0);
        if (lane == 0) bits[base + t] = m;
    }
}

// ---------------------------------------------------------------------------
// Kernel A (loopable): h = x@W + b; s_src/s_dst; hswz fragment-major.
#define GH_KT 128
__global__ __launch_bounds__(256) void gat_h(
    const float* __restrict__ x, const float* __restrict__ W,
    const float* __restrict__ bias, const float* __restrict__ a,
    const float* __restrict__ a_b,
    float* __restrict__ s_src, float* __restrict__ s_dst,
    unsigned short* __restrict__ hswz, int reps)
{
    __shared__ __align__(16) float xlds[2][16][GH_KT];

    const int lane = threadIdx.x & 63;
    const int wave = threadIdx.x >> 6;
    const int i0 = blockIdx.x * 16;
    const int r0 = i0 + wave * 4;

    auto stage = [&](int buf, int k0) {
        #pragma unroll
        for (int d = 0; d < 2; ++d) {
            const int row = wave * 4 + d * 2 + (lane >> 5);
            const float* gp = x + (size_t)(i0 + row) * FIN + k0 + (lane & 31) * 4;
            __builtin_amdgcn_global_load_lds(
                (const __attribute__((address_space(1))) float*)gp,
                (__attribute__((address_space(3))) float*)&xlds[buf][wave * 4 + d * 2][0],
                16, 0, 0);
        }
    };

    for (int rep = 0; rep < reps; ++rep) {
        asm volatile("" ::: "memory");
        float acc0 = 0.f, acc1 = 0.f, acc2 = 0.f, acc3 = 0.f;
        stage(0, 0);
        for (int kt = 0; kt < FIN / GH_KT; ++kt) {
            asm volatile("s_waitcnt vmcnt(0)" ::: "memory");
            __builtin_amdgcn_sched_barrier(0);
            if (kt + 1 < FIN / GH_KT) stage((kt + 1) & 1, (kt + 1) * GH_KT);

            const float* xt = &xlds[kt & 1][wave * 4][0];
            const int k0 = kt * GH_KT;
            #pragma unroll 4
            for (int k4 = 0; k4 < GH_KT / 4; ++k4) {
                float w0 = W[(k0 + k4 * 4 + 0) * FOUT + lane];
                float w1 = W[(k0 + k4 * 4 + 1) * FOUT + lane];
                float w2 = W[(k0 + k4 * 4 + 2) * FOUT + lane];
                float w3 = W[(k0 + k4 * 4 + 3) * FOUT + lane];
                float4 xa = *reinterpret_cast<const float4*>(xt + 0 * GH_KT + k4 * 4);
                float4 xb = *reinterpret_cast<const float4*>(xt + 1 * GH_KT + k4 * 4);
                float4 xc = *reinterpret_cast<const float4*>(xt + 2 * GH_KT + k4 * 4);
                float4 xd = *reinterpret_cast<const float4*>(xt + 3 * GH_KT + k4 * 4);
                acc0 = fmaf(xa.w, w3, fmaf(xa.z, w2, fmaf(xa.y, w1, fmaf(xa.x, w0, acc0))));
                acc1 = fmaf(xb.w, w3, fmaf(xb.z, w2, fmaf(xb.y, w1, fmaf(xb.x, w0, acc1))));
                acc2 = fmaf(xc.w, w3, fmaf(xc.z, w2, fmaf(xc.y, w1, fmaf(xc.x, w0, acc2))));
                acc3 = fmaf(xd.w, w3, fmaf(xd.z, w2, fmaf(xd.y, w1, fmaf(xd.x, w0, acc3))));
            }
        }

        float bb = bias[lane];
        acc0 += bb; acc1 += bb; acc2 += bb; acc3 += bb;

        {
            const int ks = r0 >> 5;
            const int n = lane >> 4;
            const int lane_dst = (lane & 15) + (((r0 >> 3) & 3) << 4);
            const int e0 = r0 & 7;
            ushort4 pk;
            pk.x = (unsigned short)f2bf_bits(acc0);
            pk.y = (unsigned short)f2bf_bits(acc1);
            pk.z = (unsigned short)f2bf_bits(acc2);
            pk.w = (unsigned short)f2bf_bits(acc3);
            *reinterpret_cast<ushort4*>(
                hswz + (size_t)((ks * 4 + n) * 64 + lane_dst) * 8 + e0) = pk;
        }

        float asrc = a[lane], adst = a[FOUT + lane];
        float ab = a_b[0];
        float ss0 = acc0 * asrc, ss1 = acc1 * asrc, ss2 = acc2 * asrc, ss3 = acc3 * asrc;
        float sd0 = acc0 * adst, sd1 = acc1 * adst, sd2 = acc2 * adst, sd3 = acc3 * adst;
        #pragma unroll
        for (int m = 32; m >= 1; m >>= 1) {
            ss0 += __shfl_xor(ss0, m); ss1 += __shfl_xor(ss1, m);
            ss2 += __shfl_xor(ss2, m); ss3 += __shfl_xor(ss3, m);
            sd0 += __shfl_xor(sd0, m); sd1 += __shfl_xor(sd1, m);
            sd2 += __shfl_xor(sd2, m); sd3 += __shfl_xor(sd3, m);
        }
        if (lane == 0) {
            float4 vs = { ss0 + ab, ss1 + ab, ss2 + ab, ss3 + ab };
            float4 vd = { sd0, sd1, sd2, sd3 };
            *reinterpret_cast<float4*>(s_src + r0) = vs;
            *reinterpret_cast<float4*>(s_dst + r0) = vd;
        }
    }
}

// ---------------------------------------------------------------------------
// Kernel B variants. VAR: 0=FULL (real, writes out), 1=CVTPK full (ws),
// 2=MATH only (no hswz/MFMA; af asm-kept), 3=LOADS only (all asm-kept).
template<int VAR>
__global__ __launch_bounds__(512) void gat_attn_v(
    const unsigned int* __restrict__ bits,
    const float* __restrict__ s_src,
    const float* __restrict__ s_dst,
    const unsigned short* __restrict__ hswz,
    float* __restrict__ outp, int reps)
{
    __shared__ __align__(16) char bsmem[16640];   // bits tile, row stride 1040
    __shared__ __align__(16) char rsmem[33280];   // reduction buffers

    const int lane = threadIdx.x & 63;
    const int wave = threadIdx.x >> 6;
    const int i0 = blockIdx.x * 16;
    const int r = lane & 15;
    const int g = lane >> 4;

    #pragma unroll
    for (int i = 0; i < 2; ++i) {
        const int c = threadIdx.x + i * 512;
        const int row = c >> 6, col = c & 63;
        uint4 v = *reinterpret_cast<const uint4*>(bits + (size_t)(i0 + row) * 256 + col * 4);
        *reinterpret_cast<uint4*>(bsmem + row * 1040 + col * 16) = v;
    }
    __syncthreads();

    const float ssrc = s_src[i0 + r];
    const char* bl = bsmem + r * 1040 + (wave << 3);

    for (int rep = 0; rep < reps; ++rep) {
        asm volatile("" ::: "memory");
        floatx4 acc[4] = { {0.f,0.f,0.f,0.f},{0.f,0.f,0.f,0.f},
                           {0.f,0.f,0.f,0.f},{0.f,0.f,0.f,0.f} };
        float denom = 0.f;

        for (int s = 0; s < 16; ++s) {
            uint2 bw = *reinterpret_cast<const uint2*>(bl + s * 64);
            if (VAR == 3) asm volatile("" :: "v"(bw.x), "v"(bw.y));
            #pragma unroll
            for (int kk = 0; kk < 2; ++kk) {
                const int jb = s * 512 + wave * 64 + kk * 32 + g * 8;
                float4 S0 = *reinterpret_cast<const float4*>(s_dst + jb);
                float4 S1 = *reinterpret_cast<const float4*>(s_dst + jb + 4);
                short8 af;
                if (VAR != 3) {
                    const unsigned byte = ((kk ? bw.y : bw.x) >> (g * 8)) & 0xffu;
                    float e0 = ssrc + S0.x, e1 = ssrc + S0.y, e2 = ssrc + S0.z, e3 = ssrc + S0.w;
                    float e4 = ssrc + S1.x, e5 = ssrc + S1.y, e6 = ssrc + S1.z, e7 = ssrc + S1.w;
                    e0 = fmaxf(e0, LRELU_ALPHA * e0); e1 = fmaxf(e1, LRELU_ALPHA * e1);
                    e2 = fmaxf(e2, LRELU_ALPHA * e2); e3 = fmaxf(e3, LRELU_ALPHA * e3);
                    e4 = fmaxf(e4, LRELU_ALPHA * e4); e5 = fmaxf(e5, LRELU_ALPHA * e5);
                    e6 = fmaxf(e6, LRELU_ALPHA * e6); e7 = fmaxf(e7, LRELU_ALPHA * e7);
                    float p0 = (byte & 1u)   ? __expf(e0) : 0.f;
                    float p1 = (byte & 2u)   ? __expf(e1) : 0.f;
                    float p2 = (byte & 4u)   ? __expf(e2) : 0.f;
                    float p3 = (byte & 8u)   ? __expf(e3) : 0.f;
                    float p4 = (byte & 16u)  ? __expf(e4) : 0.f;
                    float p5 = (byte & 32u)  ? __expf(e5) : 0.f;
                    float p6 = (byte & 64u)  ? __expf(e6) : 0.f;
                    float p7 = (byte & 128u) ? __expf(e7) : 0.f;
                    denom += ((p0 + p1) + (p2 + p3)) + ((p4 + p5) + (p6 + p7));
                    if (VAR == 1) {
                        unsigned r01, r23, r45, r67;
                        asm("v_cvt_pk_bf16_f32 %0, %1, %2" : "=v"(r01) : "v"(p0), "v"(p1));
                        asm("v_cvt_pk_bf16_f32 %0, %1, %2" : "=v"(r23) : "v"(p2), "v"(p3));
                        asm("v_cvt_pk_bf16_f32 %0, %1, %2" : "=v"(r45) : "v"(p4), "v"(p5));
                        asm("v_cvt_pk_bf16_f32 %0, %1, %2" : "=v"(r67) : "v"(p6), "v"(p7));
                        int4 ai = { (int)r01, (int)r23, (int)r45, (int)r67 };
                        af = *reinterpret_cast<short8*>(&ai);
                    } else {
                        af[0] = f2bf_bits(p0); af[1] = f2bf_bits(p1);
                        af[2] = f2bf_bits(p2); af[3] = f2bf_bits(p3);
                        af[4] = f2bf_bits(p4); af[5] = f2bf_bits(p5);
                        af[6] = f2bf_bits(p6); af[7] = f2bf_bits(p7);
                    }
                } else {
                    asm volatile("" :: "v"(S0.x), "v"(S0.y), "v"(S0.z), "v"(S0.w));
                    asm volatile("" :: "v"(S1.x), "v"(S1.y), "v"(S1.z), "v"(S1.w));
                }
                if (VAR == 2) {
                    int4 ai = *reinterpret_cast<int4*>(&af);
                    asm volatile("" :: "v"(ai.x), "v"(ai.y), "v"(ai.z), "v"(ai.w));
                } else {
                    const int ks = s * 16 + wave * 2 + kk;
                    #pragma unroll
                    for (int n = 0; n < 4; ++n) {
                        short8 bf = *reinterpret_cast<const short8*>(
                            hswz + (size_t)((ks * 4 + n) * 64 + lane) * 8);
                        if (VAR == 3) {
                            int4 bi = *reinterpret_cast<int4*>(&bf);
                            asm volatile("" :: "v"(bi.x), "v"(bi.y), "v"(bi.z), "v"(bi.w));
                        } else {
                            acc[n] = __builtin_amdgcn_mfma_f32_16x16x32_bf16(af, bf, acc[n], 0, 0, 0);
                        }
                    }
                }
            }
        }

        if (VAR == 0 || VAR == 1) {
            denom += __shfl_xor(denom, 16);
            denom += __shfl_xor(denom, 32);
            __syncthreads();
            floatx4* redbuf = (floatx4*)rsmem;
            float* dred = (float*)(rsmem + 32768);
            #pragma unroll
            for (int n = 0; n < 4; ++n) redbuf[(wave * 4 + n) * 64 + lane] = acc[n];
            if (lane < 16) dred[wave * 16 + lane] = denom;
            __syncthreads();
            if (wave < 4) {
                floatx4 facc = redbuf[wave * 64 + lane];
                #pragma unroll
                for (int v = 1; v < 8; ++v) facc += redbuf[(v * 4 + wave) * 64 + lane];
                #pragma unroll
                for (int e = 0; e < 4; ++e) {
                    const int r2 = (lane >> 4) * 4 + e;
                    float dn = 0.f;
                    #pragma unroll
                    for (int v = 0; v < 8; ++v) dn += dred[v * 16 + r2];
                    float val = facc[e] / dn;
                    val = val > 0.f ? val : (__expf(val) - 1.f);
                    outp[(size_t)(i0 + r2) * FOUT + wave * 16 + (lane & 15)] = val;
                }
            }
        } else if (VAR == 2) {
            outp[(size_t)blockIdx.x * 512 + threadIdx.x] = denom;
        } else {
            if (lane == 0) outp[blockIdx.x * 8 + wave] = 1.0f;
        }
    }
}

extern "C" void kernel_launch(void* const* d_in, const int* in_sizes, int n_in,
                              void* d_out, int out_size, void* d_ws, size_t ws_size,
                              hipStream_t stream) {
    const float* x   = (const float*)d_in[0];
    const int*   adj = (const int*)d_in[1];
    const float* W   = (const float*)d_in[2];
    const float* b   = (const float*)d_in[3];
    const float* a   = (const float*)d_in[4];
    const float* a_b = (const float*)d_in[5];
    float* out = (float*)d_out;

    char* ws = (char*)d_ws;
    float* s_src = (float*)ws;
    float* s_dst = (float*)(ws + 32 * 1024);
    unsigned short* hswz = (unsigned short*)(ws + 64 * 1024);
    unsigned long long* bitsW = (unsigned long long*)(ws + 64 * 1024 + 1024 * 1024);
    const unsigned int* bitsR = (const unsigned int*)bitsW;
    float* v1out = (float*)(ws + 16u * 1024 * 1024);
    float* v2out = (float*)(ws + 20u * 1024 * 1024);
    float* v3out = (float*)(ws + 24u * 1024 * 1024);

    hipLaunchKernelGGL(adj_bits, dim3(N_NODES / 4), dim3(256), 0, stream, adj, bitsW);
    hipLaunchKernelGGL(gat_h, dim3(N_NODES / 16), dim3(256), 0, stream,
                       x, W, b, a, a_b, s_src, s_dst, hswz, 12);
    // MEASUREMENT ROUND: looped dispatches so each clears the ~155us top-5 bar
    // and exposes its own counters. VAR0 is the real (r6-identical) kernel.
    hipLaunchKernelGGL((gat_attn_v<0>), dim3(N_NODES / 16), dim3(512), 0, stream,
                       bitsR, s_src, s_dst, hswz, out, 3);
    hipLaunchKernelGGL((gat_attn_v<1>), dim3(N_NODES / 16), dim3(512), 0, stream,
                       bitsR, s_src, s_dst, hswz, v1out, 6);
    hipLaunchKernelGGL((gat_attn_v<2>), dim3(N_NODES / 16), dim3(512), 0, stream,
                       bitsR, s_src, s_dst, hswz, v2out, 10);
    hipLaunchKernelGGL((gat_attn_v<3>), dim3(N_NODES / 16), dim3(512), 0, stream,
                       bitsR, s_src, s_dst, hswz, v3out, 12);
}

// Round 8
// 211.972 us; speedup vs baseline: 4.9893x; 4.9893x over previous
//
#include <hip/hip_runtime.h>
#include <hip/hip_bf16.h>

#define N_NODES 8192
#define FIN 512
#define FOUT 64

typedef __attribute__((ext_vector_type(8))) short short8;
typedef __attribute__((ext_vector_type(4))) float floatx4;

static __device__ __forceinline__ short f2bf_bits(float x) {
    union { __hip_bfloat16 b; short s; } u; u.b = __float2bfloat16(x); return u.s;
}

// ---------------------------------------------------------------------------
// Kernel 1 (fused prep). Blocks [0,512): gat_h (h=x@W+b, hswz frag-major,
// per-node exp pairs EFi/EFd). Blocks [512,2560): adj -> bitmask compress.
// gat_h blocks first so their 26us hides under the 41us adj stream.
#define GH_KT 128
__global__ __launch_bounds__(256) void prep(
    const int* __restrict__ adj, unsigned long long* __restrict__ bits,
    const float* __restrict__ x, const float* __restrict__ W,
    const float* __restrict__ bias, const float* __restrict__ a,
    const float* __restrict__ a_b,
    float2* __restrict__ EFi, float2* __restrict__ EFd,
    unsigned short* __restrict__ hswz)
{
    __shared__ __align__(16) float xlds[2][16][GH_KT];   // 16 KB (gat_h branch only)

    const int lane = threadIdx.x & 63;
    const int wave = threadIdx.x >> 6;

    if (blockIdx.x >= 512) {
        // ---- adj_bits: pure streaming compress, wave handles one row ----
        const int wid = (blockIdx.x - 512) * 4 + wave;
        const size_t base = (size_t)wid * 128;
        const int* src = adj + base * 64 + lane;
        #pragma unroll 8
        for (int t = 0; t < 128; ++t) {
            int v = src[t * 64];
            unsigned long long m = __ballot(v > 0);
            if (lane == 0) bits[base + t] = m;
        }
        return;
    }

    // ---- gat_h: block = 16 rows x 4 waves; wave owns rows 4w..4w+3 ----
    const int i0 = blockIdx.x * 16;
    const int r0 = i0 + wave * 4;

    auto stage = [&](int buf, int k0) {
        #pragma unroll
        for (int d = 0; d < 2; ++d) {
            const float* gp = x + (size_t)(i0 + wave * 4 + d * 2 + (lane >> 5)) * FIN
                            + k0 + (lane & 31) * 4;
            __builtin_amdgcn_global_load_lds(
                (const __attribute__((address_space(1))) float*)gp,
                (__attribute__((address_space(3))) float*)&xlds[buf][wave * 4 + d * 2][0],
                16, 0, 0);
        }
    };

    float acc0 = 0.f, acc1 = 0.f, acc2 = 0.f, acc3 = 0.f;
    stage(0, 0);
    for (int kt = 0; kt < FIN / GH_KT; ++kt) {
        asm volatile("s_waitcnt vmcnt(0)" ::: "memory");
        __builtin_amdgcn_sched_barrier(0);
        if (kt + 1 < FIN / GH_KT) stage((kt + 1) & 1, (kt + 1) * GH_KT);

        const float* xt = &xlds[kt & 1][wave * 4][0];
        const int k0 = kt * GH_KT;
        #pragma unroll 4
        for (int k4 = 0; k4 < GH_KT / 4; ++k4) {
            float w0 = W[(k0 + k4 * 4 + 0) * FOUT + lane];
            float w1 = W[(k0 + k4 * 4 + 1) * FOUT + lane];
            float w2 = W[(k0 + k4 * 4 + 2) * FOUT + lane];
            float w3 = W[(k0 + k4 * 4 + 3) * FOUT + lane];
            float4 xa = *reinterpret_cast<const float4*>(xt + 0 * GH_KT + k4 * 4);
            float4 xb = *reinterpret_cast<const float4*>(xt + 1 * GH_KT + k4 * 4);
            float4 xc = *reinterpret_cast<const float4*>(xt + 2 * GH_KT + k4 * 4);
            float4 xd = *reinterpret_cast<const float4*>(xt + 3 * GH_KT + k4 * 4);
            acc0 = fmaf(xa.w, w3, fmaf(xa.z, w2, fmaf(xa.y, w1, fmaf(xa.x, w0, acc0))));
            acc1 = fmaf(xb.w, w3, fmaf(xb.z, w2, fmaf(xb.y, w1, fmaf(xb.x, w0, acc1))));
            acc2 = fmaf(xc.w, w3, fmaf(xc.z, w2, fmaf(xc.y, w1, fmaf(xc.x, w0, acc2))));
            acc3 = fmaf(xd.w, w3, fmaf(xd.z, w2, fmaf(xd.y, w1, fmaf(xd.x, w0, acc3))));
        }
    }

    float bb = bias[lane];
    acc0 += bb; acc1 += bb; acc2 += bb; acc3 += bb;

    {   // fragment-major bf16 store (4 rows -> ushort4 at e0 = r0&7)
        const int ks = r0 >> 5;
        const int n = lane >> 4;
        const int lane_dst = (lane & 15) + (((r0 >> 3) & 3) << 4);
        const int e0 = r0 & 7;
        ushort4 pk;
        pk.x = (unsigned short)f2bf_bits(acc0);
        pk.y = (unsigned short)f2bf_bits(acc1);
        pk.z = (unsigned short)f2bf_bits(acc2);
        pk.w = (unsigned short)f2bf_bits(acc3);
        *reinterpret_cast<ushort4*>(
            hswz + (size_t)((ks * 4 + n) * 64 + lane_dst) * 8 + e0) = pk;
    }

    float asrc = a[lane], adst = a[FOUT + lane];
    float ab = a_b[0];
    float ss0 = acc0 * asrc, ss1 = acc1 * asrc, ss2 = acc2 * asrc, ss3 = acc3 * asrc;
    float sd0 = acc0 * adst, sd1 = acc1 * adst, sd2 = acc2 * adst, sd3 = acc3 * adst;
    #pragma unroll
    for (int m = 32; m >= 1; m >>= 1) {
        ss0 += __shfl_xor(ss0, m); ss1 += __shfl_xor(ss1, m);
        ss2 += __shfl_xor(ss2, m); ss3 += __shfl_xor(ss3, m);
        sd0 += __shfl_xor(sd0, m); sd1 += __shfl_xor(sd1, m);
        sd2 += __shfl_xor(sd2, m); sd3 += __shfl_xor(sd3, m);
    }
    if (lane == 0) {
        // exp-factor pairs: i-side uses si (a_b folded), j-side uses dj
        float si0 = ss0 + ab, si1 = ss1 + ab, si2 = ss2 + ab, si3 = ss3 + ab;
        EFi[r0 + 0] = make_float2(__expf(si0), __expf(0.2f * si0));
        EFi[r0 + 1] = make_float2(__expf(si1), __expf(0.2f * si1));
        EFi[r0 + 2] = make_float2(__expf(si2), __expf(0.2f * si2));
        EFi[r0 + 3] = make_float2(__expf(si3), __expf(0.2f * si3));
        EFd[r0 + 0] = make_float2(__expf(sd0), __expf(0.2f * sd0));
        EFd[r0 + 1] = make_float2(__expf(sd1), __expf(0.2f * sd1));
        EFd[r0 + 2] = make_float2(__expf(sd2), __expf(0.2f * sd2));
        EFd[r0 + 3] = make_float2(__expf(sd3), __expf(0.2f * sd3));
    }
}

// ---------------------------------------------------------------------------
// Kernel 2: gat_attn. p = adj ? (Ei*Ed > 1 ? Ei*Ed : Fi*Fd) : 0  — no exp,
// no lrelu, no software bf16 convert (cvt_pk). bits from LDS; hswz frag loads
// from L2; MFMA accumulate; cross-wave reduce + denom + ELU epilogue.
__global__ __launch_bounds__(512) void gat_attn(
    const unsigned int* __restrict__ bits,
    const float2* __restrict__ EFi,
    const float2* __restrict__ EFd,
    const unsigned short* __restrict__ hswz,
    float* __restrict__ out)
{
    __shared__ __align__(16) char bsmem[16640];   // bits tile, row stride 1040
    __shared__ __align__(16) char rsmem[33280];   // reduction buffers

    const int lane = threadIdx.x & 63;
    const int wave = threadIdx.x >> 6;
    const int i0 = blockIdx.x * 16;
    const int r = lane & 15;
    const int g = lane >> 4;

    #pragma unroll
    for (int i = 0; i < 2; ++i) {
        const int c = threadIdx.x + i * 512;
        const int row = c >> 6, col = c & 63;
        uint4 v = *reinterpret_cast<const uint4*>(bits + (size_t)(i0 + row) * 256 + col * 4);
        *reinterpret_cast<uint4*>(bsmem + row * 1040 + col * 16) = v;
    }
    __syncthreads();

    const float2 efi = EFi[i0 + r];
    const float Es = efi.x, Fs = efi.y;
    const char* bl = bsmem + r * 1040 + (wave << 3);

    floatx4 acc[4] = { {0.f,0.f,0.f,0.f},{0.f,0.f,0.f,0.f},
                       {0.f,0.f,0.f,0.f},{0.f,0.f,0.f,0.f} };
    float denom = 0.f;

    for (int s = 0; s < 16; ++s) {
        uint2 bw = *reinterpret_cast<const uint2*>(bl + s * 64);
        #pragma unroll
        for (int kk = 0; kk < 2; ++kk) {
            const unsigned byte = ((kk ? bw.y : bw.x) >> (g * 8)) & 0xffu;
            const int jb = s * 512 + wave * 64 + kk * 32 + g * 8;
            const float4* ef = reinterpret_cast<const float4*>(EFd + jb);
            float4 q0 = ef[0];   // {E0,F0,E1,F1}
            float4 q1 = ef[1];   // {E2,F2,E3,F3}
            float4 q2 = ef[2];
            float4 q3 = ef[3];
            float m0 = Es * q0.x, f0 = Fs * q0.y;
            float m1 = Es * q0.z, f1 = Fs * q0.w;
            float m2 = Es * q1.x, f2 = Fs * q1.y;
            float m3 = Es * q1.z, f3 = Fs * q1.w;
            float m4 = Es * q2.x, f4 = Fs * q2.y;
            float m5 = Es * q2.z, f5 = Fs * q2.w;
            float m6 = Es * q3.x, f6 = Fs * q3.y;
            float m7 = Es * q3.z, f7 = Fs * q3.w;
            float p0 = m0 > 1.0f ? m0 : f0;  p0 = (byte & 1u)   ? p0 : 0.f;
            float p1 = m1 > 1.0f ? m1 : f1;  p1 = (byte & 2u)   ? p1 : 0.f;
            float p2 = m2 > 1.0f ? m2 : f2;  p2 = (byte & 4u)   ? p2 : 0.f;
            float p3 = m3 > 1.0f ? m3 : f3;  p3 = (byte & 8u)   ? p3 : 0.f;
            float p4 = m4 > 1.0f ? m4 : f4;  p4 = (byte & 16u)  ? p4 : 0.f;
            float p5 = m5 > 1.0f ? m5 : f5;  p5 = (byte & 32u)  ? p5 : 0.f;
            float p6 = m6 > 1.0f ? m6 : f6;  p6 = (byte & 64u)  ? p6 : 0.f;
            float p7 = m7 > 1.0f ? m7 : f7;  p7 = (byte & 128u) ? p7 : 0.f;
            denom += ((p0 + p1) + (p2 + p3)) + ((p4 + p5) + (p6 + p7));
            unsigned r01, r23, r45, r67;
            asm("v_cvt_pk_bf16_f32 %0, %1, %2" : "=v"(r01) : "v"(p0), "v"(p1));
            asm("v_cvt_pk_bf16_f32 %0, %1, %2" : "=v"(r23) : "v"(p2), "v"(p3));
            asm("v_cvt_pk_bf16_f32 %0, %1, %2" : "=v"(r45) : "v"(p4), "v"(p5));
            asm("v_cvt_pk_bf16_f32 %0, %1, %2" : "=v"(r67) : "v"(p6), "v"(p7));
            int4 ai = { (int)r01, (int)r23, (int)r45, (int)r67 };
            short8 af = *reinterpret_cast<short8*>(&ai);
            const int ks = s * 16 + wave * 2 + kk;
            #pragma unroll
            for (int n = 0; n < 4; ++n) {
                short8 bf = *reinterpret_cast<const short8*>(
                    hswz + (size_t)((ks * 4 + n) * 64 + lane) * 8);
                acc[n] = __builtin_amdgcn_mfma_f32_16x16x32_bf16(af, bf, acc[n], 0, 0, 0);
            }
        }
    }

    denom += __shfl_xor(denom, 16);
    denom += __shfl_xor(denom, 32);

    __syncthreads();
    floatx4* redbuf = (floatx4*)rsmem;
    float* dred = (float*)(rsmem + 32768);
    #pragma unroll
    for (int n = 0; n < 4; ++n) redbuf[(wave * 4 + n) * 64 + lane] = acc[n];
    if (lane < 16) dred[wave * 16 + lane] = denom;
    __syncthreads();

    if (wave < 4) {
        floatx4 facc = redbuf[wave * 64 + lane];
        #pragma unroll
        for (int v = 1; v < 8; ++v) facc += redbuf[(v * 4 + wave) * 64 + lane];
        #pragma unroll
        for (int e = 0; e < 4; ++e) {
            const int r2 = (lane >> 4) * 4 + e;
            float dn = 0.f;
            #pragma unroll
            for (int v = 0; v < 8; ++v) dn += dred[v * 16 + r2];
            float val = facc[e] / dn;
            val = val > 0.f ? val : (__expf(val) - 1.f);   // ELU
            out[(size_t)(i0 + r2) * FOUT + wave * 16 + (lane & 15)] = val;
        }
    }
}

extern "C" void kernel_launch(void* const* d_in, const int* in_sizes, int n_in,
                              void* d_out, int out_size, void* d_ws, size_t ws_size,
                              hipStream_t stream) {
    const float* x   = (const float*)d_in[0];
    const int*   adj = (const int*)d_in[1];
    const float* W   = (const float*)d_in[2];
    const float* b   = (const float*)d_in[3];
    const float* a   = (const float*)d_in[4];
    const float* a_b = (const float*)d_in[5];
    float* out = (float*)d_out;

    char* ws = (char*)d_ws;
    float2* EFi = (float2*)ws;                                   // 64 KB
    float2* EFd = (float2*)(ws + 64 * 1024);                     // 64 KB
    unsigned short* hswz = (unsigned short*)(ws + 128 * 1024);   // 1 MB
    unsigned long long* bitsW = (unsigned long long*)(ws + 128 * 1024 + 1024 * 1024); // 8 MB
    const unsigned int* bitsR = (const unsigned int*)bitsW;

    hipLaunchKernelGGL(prep, dim3(512 + N_NODES / 4), dim3(256), 0, stream,
                       adj, bitsW, x, W, b, a, a_b, EFi, EFd, hswz);
    hipLaunchKernelGGL(gat_attn, dim3(N_NODES / 16), dim3(512), 0, stream,
                       bitsR, EFi, EFd, hswz, out);
}

// Round 9
// 175.256 us; speedup vs baseline: 6.0346x; 1.2095x over previous
//
#include <hip/hip_runtime.h>
#include <hip/hip_bf16.h>

#define N_NODES 8192
#define FIN 512
#define FOUT 64

typedef __attribute__((ext_vector_type(8))) short short8;
typedef __attribute__((ext_vector_type(4))) float floatx4;

static __device__ __forceinline__ short f2bf_bits(float x) {
    union { __hip_bfloat16 b; short s; } u; u.b = __float2bfloat16(x); return u.s;
}

// ---------------------------------------------------------------------------
// Kernel 1: adj (int32 0/1, 256 MB) -> bitmask (8 MB). Pure streaming,
// decoupled from all compute (r8 lesson: fusing poisons both sides).
__global__ __launch_bounds__(256) void adj_bits(
    const int* __restrict__ adj, unsigned long long* __restrict__ bits)
{
    const int lane = threadIdx.x & 63;
    const int wid = blockIdx.x * 4 + (threadIdx.x >> 6);
    const size_t base = (size_t)wid * 128;
    const int* src = adj + base * 64 + lane;
    #pragma unroll 8
    for (int t = 0; t < 128; ++t) {
        int v = src[t * 64];
        unsigned long long m = __ballot(v > 0);
        if (lane == 0) bits[base + t] = m;
    }
}

// ---------------------------------------------------------------------------
// Kernel 2: gat_h — ONE row per wave (8192 waves = 8 waves/SIMD, 4x the TLP
// of the old 4-row version). x-row loads are wave-uniform (readfirstlane base
// -> scalar path); W loads coalesced, 16 independent per chunk; 4-way split
// accumulators. Epilogue: hswz frag-major bf16 scatter + exp-factor pairs.
__global__ __launch_bounds__(256) void gat_h(
    const float* __restrict__ x, const float* __restrict__ W,
    const float* __restrict__ bias, const float* __restrict__ a,
    const float* __restrict__ a_b,
    float2* __restrict__ EFi, float2* __restrict__ EFd,
    unsigned short* __restrict__ hswz)
{
    const int lane = threadIdx.x & 63;
    const int wave = threadIdx.x >> 6;
    const int r = __builtin_amdgcn_readfirstlane((int)(blockIdx.x * 4 + wave));
    const float* xr = x + (size_t)r * FIN;
    const float* Wl = W + lane;

    float acc0 = 0.f, acc1 = 0.f, acc2 = 0.f, acc3 = 0.f;
    #pragma unroll 2
    for (int k0 = 0; k0 < FIN; k0 += 16) {
        float4 xa = *reinterpret_cast<const float4*>(xr + k0);
        float4 xb = *reinterpret_cast<const float4*>(xr + k0 + 4);
        float4 xc = *reinterpret_cast<const float4*>(xr + k0 + 8);
        float4 xd = *reinterpret_cast<const float4*>(xr + k0 + 12);
        float w0  = Wl[(k0 +  0) * FOUT];
        float w1  = Wl[(k0 +  1) * FOUT];
        float w2  = Wl[(k0 +  2) * FOUT];
        float w3  = Wl[(k0 +  3) * FOUT];
        float w4  = Wl[(k0 +  4) * FOUT];
        float w5  = Wl[(k0 +  5) * FOUT];
        float w6  = Wl[(k0 +  6) * FOUT];
        float w7  = Wl[(k0 +  7) * FOUT];
        float w8  = Wl[(k0 +  8) * FOUT];
        float w9  = Wl[(k0 +  9) * FOUT];
        float w10 = Wl[(k0 + 10) * FOUT];
        float w11 = Wl[(k0 + 11) * FOUT];
        float w12 = Wl[(k0 + 12) * FOUT];
        float w13 = Wl[(k0 + 13) * FOUT];
        float w14 = Wl[(k0 + 14) * FOUT];
        float w15 = Wl[(k0 + 15) * FOUT];
        acc0 = fmaf(xa.x, w0,  acc0);
        acc1 = fmaf(xa.y, w1,  acc1);
        acc2 = fmaf(xa.z, w2,  acc2);
        acc3 = fmaf(xa.w, w3,  acc3);
        acc0 = fmaf(xb.x, w4,  acc0);
        acc1 = fmaf(xb.y, w5,  acc1);
        acc2 = fmaf(xb.z, w6,  acc2);
        acc3 = fmaf(xb.w, w7,  acc3);
        acc0 = fmaf(xc.x, w8,  acc0);
        acc1 = fmaf(xc.y, w9,  acc1);
        acc2 = fmaf(xc.z, w10, acc2);
        acc3 = fmaf(xc.w, w11, acc3);
        acc0 = fmaf(xd.x, w12, acc0);
        acc1 = fmaf(xd.y, w13, acc1);
        acc2 = fmaf(xd.z, w14, acc2);
        acc3 = fmaf(xd.w, w15, acc3);
    }
    float h = ((acc0 + acc1) + (acc2 + acc3)) + bias[lane];

    // hswz frag-major store (same layout the validated gat_attn reads):
    // hswz[((ks*4+n)*64 + lane_dst)*8 + e], ks=r>>5, n=lane>>4,
    // lane_dst=(lane&15)+(((r>>3)&3)<<4), e=r&7. One ushort per lane.
    {
        const int ks = r >> 5;
        const int n = lane >> 4;
        const int lane_dst = (lane & 15) + (((r >> 3) & 3) << 4);
        hswz[(size_t)((ks * 4 + n) * 64 + lane_dst) * 8 + (r & 7)] =
            (unsigned short)f2bf_bits(h);
    }

    float ss = h * a[lane];
    float sd = h * a[FOUT + lane];
    #pragma unroll
    for (int m = 32; m >= 1; m >>= 1) {
        ss += __shfl_xor(ss, m);
        sd += __shfl_xor(sd, m);
    }
    if (lane == 0) {
        float si = ss + a_b[0];
        EFi[r] = make_float2(__expf(si), __expf(0.2f * si));
        EFd[r] = make_float2(__expf(sd), __expf(0.2f * sd));
    }
}

// ---------------------------------------------------------------------------
// Kernel 3: gat_attn (bit-identical to r8's validated version).
// p = adj ? (Ei*Ed > 1 ? Ei*Ed : Fi*Fd) : 0 — no exp/lrelu/software-convert.
__global__ __launch_bounds__(512) void gat_attn(
    const unsigned int* __restrict__ bits,
    const float2* __restrict__ EFi,
    const float2* __restrict__ EFd,
    const unsigned short* __restrict__ hswz,
    float* __restrict__ out)
{
    __shared__ __align__(16) char bsmem[16640];   // bits tile, row stride 1040
    __shared__ __align__(16) char rsmem[33280];   // reduction buffers

    const int lane = threadIdx.x & 63;
    const int wave = threadIdx.x >> 6;
    const int i0 = blockIdx.x * 16;
    const int r = lane & 15;
    const int g = lane >> 4;

    #pragma unroll
    for (int i = 0; i < 2; ++i) {
        const int c = threadIdx.x + i * 512;
        const int row = c >> 6, col = c & 63;
        uint4 v = *reinterpret_cast<const uint4*>(bits + (size_t)(i0 + row) * 256 + col * 4);
        *reinterpret_cast<uint4*>(bsmem + row * 1040 + col * 16) = v;
    }
    __syncthreads();

    const float2 efi = EFi[i0 + r];
    const float Es = efi.x, Fs = efi.y;
    const char* bl = bsmem + r * 1040 + (wave << 3);

    floatx4 acc[4] = { {0.f,0.f,0.f,0.f},{0.f,0.f,0.f,0.f},
                       {0.f,0.f,0.f,0.f},{0.f,0.f,0.f,0.f} };
    float denom = 0.f;

    for (int s = 0; s < 16; ++s) {
        uint2 bw = *reinterpret_cast<const uint2*>(bl + s * 64);
        #pragma unroll
        for (int kk = 0; kk < 2; ++kk) {
            const unsigned byte = ((kk ? bw.y : bw.x) >> (g * 8)) & 0xffu;
            const int jb = s * 512 + wave * 64 + kk * 32 + g * 8;
            const float4* ef = reinterpret_cast<const float4*>(EFd + jb);
            float4 q0 = ef[0];
            float4 q1 = ef[1];
            float4 q2 = ef[2];
            float4 q3 = ef[3];
            float m0 = Es * q0.x, f0 = Fs * q0.y;
            float m1 = Es * q0.z, f1 = Fs * q0.w;
            float m2 = Es * q1.x, f2 = Fs * q1.y;
            float m3 = Es * q1.z, f3 = Fs * q1.w;
            float m4 = Es * q2.x, f4 = Fs * q2.y;
            float m5 = Es * q2.z, f5 = Fs * q2.w;
            float m6 = Es * q3.x, f6 = Fs * q3.y;
            float m7 = Es * q3.z, f7 = Fs * q3.w;
            float p0 = m0 > 1.0f ? m0 : f0;  p0 = (byte & 1u)   ? p0 : 0.f;
            float p1 = m1 > 1.0f ? m1 : f1;  p1 = (byte & 2u)   ? p1 : 0.f;
            float p2 = m2 > 1.0f ? m2 : f2;  p2 = (byte & 4u)   ? p2 : 0.f;
            float p3 = m3 > 1.0f ? m3 : f3;  p3 = (byte & 8u)   ? p3 : 0.f;
            float p4 = m4 > 1.0f ? m4 : f4;  p4 = (byte & 16u)  ? p4 : 0.f;
            float p5 = m5 > 1.0f ? m5 : f5;  p5 = (byte & 32u)  ? p5 : 0.f;
            float p6 = m6 > 1.0f ? m6 : f6;  p6 = (byte & 64u)  ? p6 : 0.f;
            float p7 = m7 > 1.0f ? m7 : f7;  p7 = (byte & 128u) ? p7 : 0.f;
            denom += ((p0 + p1) + (p2 + p3)) + ((p4 + p5) + (p6 + p7));
            unsigned r01, r23, r45, r67;
            asm("v_cvt_pk_bf16_f32 %0, %1, %2" : "=v"(r01) : "v"(p0), "v"(p1));
            asm("v_cvt_pk_bf16_f32 %0, %1, %2" : "=v"(r23) : "v"(p2), "v"(p3));
            asm("v_cvt_pk_bf16_f32 %0, %1, %2" : "=v"(r45) : "v"(p4), "v"(p5));
            asm("v_cvt_pk_bf16_f32 %0, %1, %2" : "=v"(r67) : "v"(p6), "v"(p7));
            int4 ai = { (int)r01, (int)r23, (int)r45, (int)r67 };
            short8 af = *reinterpret_cast<short8*>(&ai);
            const int ks = s * 16 + wave * 2 + kk;
            #pragma unroll
            for (int n = 0; n < 4; ++n) {
                short8 bf = *reinterpret_cast<const short8*>(
                    hswz + (size_t)((ks * 4 + n) * 64 + lane) * 8);
                acc[n] = __builtin_amdgcn_mfma_f32_16x16x32_bf16(af, bf, acc[n], 0, 0, 0);
            }
        }
    }

    denom += __shfl_xor(denom, 16);
    denom += __shfl_xor(denom, 32);

    __syncthreads();
    floatx4* redbuf = (floatx4*)rsmem;
    float* dred = (float*)(rsmem + 32768);
    #pragma unroll
    for (int n = 0; n < 4; ++n) redbuf[(wave * 4 + n) * 64 + lane] = acc[n];
    if (lane < 16) dred[wave * 16 + lane] = denom;
    __syncthreads();

    if (wave < 4) {
        floatx4 facc = redbuf[wave * 64 + lane];
        #pragma unroll
        for (int v = 1; v < 8; ++v) facc += redbuf[(v * 4 + wave) * 64 + lane];
        #pragma unroll
        for (int e = 0; e < 4; ++e) {
            const int r2 = (lane >> 4) * 4 + e;
            float dn = 0.f;
            #pragma unroll
            for (int v = 0; v < 8; ++v) dn += dred[v * 16 + r2];
            float val = facc[e] / dn;
            val = val > 0.f ? val : (__expf(val) - 1.f);   // ELU
            out[(size_t)(i0 + r2) * FOUT + wave * 16 + (lane & 15)] = val;
        }
    }
}

extern "C" void kernel_launch(void* const* d_in, const int* in_sizes, int n_in,
                              void* d_out, int out_size, void* d_ws, size_t ws_size,
                              hipStream_t stream) {
    const float* x   = (const float*)d_in[0];
    const int*   adj = (const int*)d_in[1];
    const float* W   = (const float*)d_in[2];
    const float* b   = (const float*)d_in[3];
    const float* a   = (const float*)d_in[4];
    const float* a_b = (const float*)d_in[5];
    float* out = (float*)d_out;

    char* ws = (char*)d_ws;
    float2* EFi = (float2*)ws;                                   // 64 KB
    float2* EFd = (float2*)(ws + 64 * 1024);                     // 64 KB
    unsigned short* hswz = (unsigned short*)(ws + 128 * 1024);   // 1 MB
    unsigned long long* bitsW = (unsigned long long*)(ws + 128 * 1024 + 1024 * 1024); // 8 MB
    const unsigned int* bitsR = (const unsigned int*)bitsW;

    hipLaunchKernelGGL(gat_h, dim3(N_NODES / 4), dim3(256), 0, stream,
                       x, W, b, a, a_b, EFi, EFd, hswz);
    hipLaunchKernelGGL(adj_bits, dim3(N_NODES / 4), dim3(256), 0, stream, adj, bitsW);
    hipLaunchKernelGGL(gat_attn, dim3(N_NODES / 16), dim3(512), 0, stream,
                       bitsR, EFi, EFd, hswz, out);
}

// Round 10
// 157.753 us; speedup vs baseline: 6.7041x; 1.1109x over previous
//
#include <hip/hip_runtime.h>
#include <hip/hip_bf16.h>

#define N_NODES 8192
#define FIN 512
#define FOUT 64
#define GH_KT 128

typedef __attribute__((ext_vector_type(8))) short short8;
typedef __attribute__((ext_vector_type(4))) float floatx4;

static __device__ __forceinline__ short f2bf_bits(float x) {
    union { __hip_bfloat16 b; short s; } u; u.b = __float2bfloat16(x); return u.s;
}

// ---------------------------------------------------------------------------
// Kernel 1: adj (int32 0/1, 256 MB) -> bitmask (8 MB). Pure streaming.
// Measured ≈43 µs ≈ 94% of achievable HBM BW — at roofline. Unchanged from r6.
__global__ __launch_bounds__(256) void adj_bits(
    const int* __restrict__ adj, unsigned long long* __restrict__ bits)
{
    const int lane = threadIdx.x & 63;
    const int wid = blockIdx.x * 4 + (threadIdx.x >> 6);
    const size_t base = (size_t)wid * 128;
    const int* src = adj + base * 64 + lane;
    #pragma unroll 8
    for (int t = 0; t < 128; ++t) {
        int v = src[t * 64];
        unsigned long long m = __ballot(v > 0);
        if (lane == 0) bits[base + t] = m;
    }
}

// ---------------------------------------------------------------------------
// Kernel 2: gat_h — r7 structure (measured 26 µs) + split-K×2 for 2× TLP.
// Block = 16 rows × 8 waves (512 thr). Wave (wr=wave&3, kh=wave>>2) computes
// rows 4wr..4wr+3 over k ∈ [kh*256, kh*256+256). Per-wave-private x tiles via
// global_load_lds, double-buffered, drain-at-top (proven r7/r8/r9 scheme).
// kh=1 waves dump partials to LDS; kh=0 waves combine + epilogue.
__global__ __launch_bounds__(512) void gat_h(
    const float* __restrict__ x, const float* __restrict__ W,
    const float* __restrict__ bias, const float* __restrict__ a,
    const float* __restrict__ a_b,
    float2* __restrict__ EFi, float2* __restrict__ EFd,
    unsigned short* __restrict__ hswz)
{
    __shared__ __align__(16) float xlds[8][2][4][GH_KT];   // 32 KB
    __shared__ float cbuf[4][4][64];                       // 4 KB

    const int lane = threadIdx.x & 63;
    const int wave = threadIdx.x >> 6;
    const int wr = wave & 3;
    const int kh = wave >> 2;
    const int i0 = blockIdx.x * 16;
    const int r0 = i0 + wr * 4;
    const int kbase = kh * 256;

    auto stage = [&](int t) {
        const int k0 = kbase + t * GH_KT;
        #pragma unroll
        for (int d = 0; d < 2; ++d) {
            const float* gp = x + (size_t)(r0 + d * 2 + (lane >> 5)) * FIN
                            + k0 + (lane & 31) * 4;
            __builtin_amdgcn_global_load_lds(
                (const __attribute__((address_space(1))) float*)gp,
                (__attribute__((address_space(3))) float*)&xlds[wave][t][d * 2][0],
                16, 0, 0);
        }
    };

    float acc0 = 0.f, acc1 = 0.f, acc2 = 0.f, acc3 = 0.f;
    stage(0);
    #pragma unroll
    for (int t = 0; t < 2; ++t) {
        asm volatile("s_waitcnt vmcnt(0)" ::: "memory");
        __builtin_amdgcn_sched_barrier(0);
        if (t == 0) stage(1);

        const float* xt = &xlds[wave][t][0][0];
        const int k0 = kbase + t * GH_KT;
        #pragma unroll 4
        for (int k4 = 0; k4 < GH_KT / 4; ++k4) {
            float w0 = W[(k0 + k4 * 4 + 0) * FOUT + lane];
            float w1 = W[(k0 + k4 * 4 + 1) * FOUT + lane];
            float w2 = W[(k0 + k4 * 4 + 2) * FOUT + lane];
            float w3 = W[(k0 + k4 * 4 + 3) * FOUT + lane];
            float4 xa = *reinterpret_cast<const float4*>(xt + 0 * GH_KT + k4 * 4);
            float4 xb = *reinterpret_cast<const float4*>(xt + 1 * GH_KT + k4 * 4);
            float4 xc = *reinterpret_cast<const float4*>(xt + 2 * GH_KT + k4 * 4);
            float4 xd = *reinterpret_cast<const float4*>(xt + 3 * GH_KT + k4 * 4);
            acc0 = fmaf(xa.w, w3, fmaf(xa.z, w2, fmaf(xa.y, w1, fmaf(xa.x, w0, acc0))));
            acc1 = fmaf(xb.w, w3, fmaf(xb.z, w2, fmaf(xb.y, w1, fmaf(xb.x, w0, acc1))));
            acc2 = fmaf(xc.w, w3, fmaf(xc.z, w2, fmaf(xc.y, w1, fmaf(xc.x, w0, acc2))));
            acc3 = fmaf(xd.w, w3, fmaf(xd.z, w2, fmaf(xd.y, w1, fmaf(xd.x, w0, acc3))));
        }
    }

    if (kh == 1) {
        cbuf[wr][0][lane] = acc0;
        cbuf[wr][1][lane] = acc1;
        cbuf[wr][2][lane] = acc2;
        cbuf[wr][3][lane] = acc3;
    }
    __syncthreads();
    if (kh == 1) return;

    float bb = bias[lane];
    acc0 += cbuf[wr][0][lane] + bb;
    acc1 += cbuf[wr][1][lane] + bb;
    acc2 += cbuf[wr][2][lane] + bb;
    acc3 += cbuf[wr][3][lane] + bb;

    {   // fragment-major bf16 store (4 rows -> ushort4 at e0 = r0&7)
        const int ks = r0 >> 5;
        const int n = lane >> 4;
        const int lane_dst = (lane & 15) + (((r0 >> 3) & 3) << 4);
        const int e0 = r0 & 7;
        ushort4 pk;
        pk.x = (unsigned short)f2bf_bits(acc0);
        pk.y = (unsigned short)f2bf_bits(acc1);
        pk.z = (unsigned short)f2bf_bits(acc2);
        pk.w = (unsigned short)f2bf_bits(acc3);
        *reinterpret_cast<ushort4*>(
            hswz + (size_t)((ks * 4 + n) * 64 + lane_dst) * 8 + e0) = pk;
    }

    float asrc = a[lane], adst = a[FOUT + lane];
    float ab = a_b[0];
    float ss0 = acc0 * asrc, ss1 = acc1 * asrc, ss2 = acc2 * asrc, ss3 = acc3 * asrc;
    float sd0 = acc0 * adst, sd1 = acc1 * adst, sd2 = acc2 * adst, sd3 = acc3 * adst;
    #pragma unroll
    for (int m = 32; m >= 1; m >>= 1) {
        ss0 += __shfl_xor(ss0, m); ss1 += __shfl_xor(ss1, m);
        ss2 += __shfl_xor(ss2, m); ss3 += __shfl_xor(ss3, m);
        sd0 += __shfl_xor(sd0, m); sd1 += __shfl_xor(sd1, m);
        sd2 += __shfl_xor(sd2, m); sd3 += __shfl_xor(sd3, m);
    }
    if (lane == 0) {
        float si0 = ss0 + ab, si1 = ss1 + ab, si2 = ss2 + ab, si3 = ss3 + ab;
        EFi[r0 + 0] = make_float2(__expf(si0), __expf(0.2f * si0));
        EFi[r0 + 1] = make_float2(__expf(si1), __expf(0.2f * si1));
        EFi[r0 + 2] = make_float2(__expf(si2), __expf(0.2f * si2));
        EFi[r0 + 3] = make_float2(__expf(si3), __expf(0.2f * si3));
        EFd[r0 + 0] = make_float2(__expf(sd0), __expf(0.2f * sd0));
        EFd[r0 + 1] = make_float2(__expf(sd1), __expf(0.2f * sd1));
        EFd[r0 + 2] = make_float2(__expf(sd2), __expf(0.2f * sd2));
        EFd[r0 + 3] = make_float2(__expf(sd3), __expf(0.2f * sd3));
    }
}

// ---------------------------------------------------------------------------
// Kernel 3: gat_attn (bit-identical to r8's validated version).
// p = adj ? (Ei*Ed > 1 ? Ei*Ed : Fi*Fd) : 0 — no exp/lrelu/software-convert.
__global__ __launch_bounds__(512) void gat_attn(
    const unsigned int* __restrict__ bits,
    const float2* __restrict__ EFi,
    const float2* __restrict__ EFd,
    const unsigned short* __restrict__ hswz,
    float* __restrict__ out)
{
    __shared__ __align__(16) char bsmem[16640];   // bits tile, row stride 1040
    __shared__ __align__(16) char rsmem[33280];   // reduction buffers

    const int lane = threadIdx.x & 63;
    const int wave = threadIdx.x >> 6;
    const int i0 = blockIdx.x * 16;
    const int r = lane & 15;
    const int g = lane >> 4;

    #pragma unroll
    for (int i = 0; i < 2; ++i) {
        const int c = threadIdx.x + i * 512;
        const int row = c >> 6, col = c & 63;
        uint4 v = *reinterpret_cast<const uint4*>(bits + (size_t)(i0 + row) * 256 + col * 4);
        *reinterpret_cast<uint4*>(bsmem + row * 1040 + col * 16) = v;
    }
    __syncthreads();

    const float2 efi = EFi[i0 + r];
    const float Es = efi.x, Fs = efi.y;
    const char* bl = bsmem + r * 1040 + (wave << 3);

    floatx4 acc[4] = { {0.f,0.f,0.f,0.f},{0.f,0.f,0.f,0.f},
                       {0.f,0.f,0.f,0.f},{0.f,0.f,0.f,0.f} };
    float denom = 0.f;

    for (int s = 0; s < 16; ++s) {
        uint2 bw = *reinterpret_cast<const uint2*>(bl + s * 64);
        #pragma unroll
        for (int kk = 0; kk < 2; ++kk) {
            const unsigned byte = ((kk ? bw.y : bw.x) >> (g * 8)) & 0xffu;
            const int jb = s * 512 + wave * 64 + kk * 32 + g * 8;
            const float4* ef = reinterpret_cast<const float4*>(EFd + jb);
            float4 q0 = ef[0];
            float4 q1 = ef[1];
            float4 q2 = ef[2];
            float4 q3 = ef[3];
            float m0 = Es * q0.x, f0 = Fs * q0.y;
            float m1 = Es * q0.z, f1 = Fs * q0.w;
            float m2 = Es * q1.x, f2 = Fs * q1.y;
            float m3 = Es * q1.z, f3 = Fs * q1.w;
            float m4 = Es * q2.x, f4 = Fs * q2.y;
            float m5 = Es * q2.z, f5 = Fs * q2.w;
            float m6 = Es * q3.x, f6 = Fs * q3.y;
            float m7 = Es * q3.z, f7 = Fs * q3.w;
            float p0 = m0 > 1.0f ? m0 : f0;  p0 = (byte & 1u)   ? p0 : 0.f;
            float p1 = m1 > 1.0f ? m1 : f1;  p1 = (byte & 2u)   ? p1 : 0.f;
            float p2 = m2 > 1.0f ? m2 : f2;  p2 = (byte & 4u)   ? p2 : 0.f;
            float p3 = m3 > 1.0f ? m3 : f3;  p3 = (byte & 8u)   ? p3 : 0.f;
            float p4 = m4 > 1.0f ? m4 : f4;  p4 = (byte & 16u)  ? p4 : 0.f;
            float p5 = m5 > 1.0f ? m5 : f5;  p5 = (byte & 32u)  ? p5 : 0.f;
            float p6 = m6 > 1.0f ? m6 : f6;  p6 = (byte & 64u)  ? p6 : 0.f;
            float p7 = m7 > 1.0f ? m7 : f7;  p7 = (byte & 128u) ? p7 : 0.f;
            denom += ((p0 + p1) + (p2 + p3)) + ((p4 + p5) + (p6 + p7));
            unsigned r01, r23, r45, r67;
            asm("v_cvt_pk_bf16_f32 %0, %1, %2" : "=v"(r01) : "v"(p0), "v"(p1));
            asm("v_cvt_pk_bf16_f32 %0, %1, %2" : "=v"(r23) : "v"(p2), "v"(p3));
            asm("v_cvt_pk_bf16_f32 %0, %1, %2" : "=v"(r45) : "v"(p4), "v"(p5));
            asm("v_cvt_pk_bf16_f32 %0, %1, %2" : "=v"(r67) : "v"(p6), "v"(p7));
            int4 ai = { (int)r01, (int)r23, (int)r45, (int)r67 };
            short8 af = *reinterpret_cast<short8*>(&ai);
            const int ks = s * 16 + wave * 2 + kk;
            #pragma unroll
            for (int n = 0; n < 4; ++n) {
                short8 bf = *reinterpret_cast<const short8*>(
                    hswz + (size_t)((ks * 4 + n) * 64 + lane) * 8);
                acc[n] = __builtin_amdgcn_mfma_f32_16x16x32_bf16(af, bf, acc[n], 0, 0, 0);
            }
        }
    }

    denom += __shfl_xor(denom, 16);
    denom += __shfl_xor(denom, 32);

    __syncthreads();
    floatx4* redbuf = (floatx4*)rsmem;
    float* dred = (float*)(rsmem + 32768);
    #pragma unroll
    for (int n = 0; n < 4; ++n) redbuf[(wave * 4 + n) * 64 + lane] = acc[n];
    if (lane < 16) dred[wave * 16 + lane] = denom;
    __syncthreads();

    if (wave < 4) {
        floatx4 facc = redbuf[wave * 64 + lane];
        #pragma unroll
        for (int v = 1; v < 8; ++v) facc += redbuf[(v * 4 + wave) * 64 + lane];
        #pragma unroll
        for (int e = 0; e < 4; ++e) {
            const int r2 = (lane >> 4) * 4 + e;
            float dn = 0.f;
            #pragma unroll
            for (int v = 0; v < 8; ++v) dn += dred[v * 16 + r2];
            float val = facc[e] / dn;
            val = val > 0.f ? val : (__expf(val) - 1.f);   // ELU
            out[(size_t)(i0 + r2) * FOUT + wave * 16 + (lane & 15)] = val;
        }
    }
}

extern "C" void kernel_launch(void* const* d_in, const int* in_sizes, int n_in,
                              void* d_out, int out_size, void* d_ws, size_t ws_size,
                              hipStream_t stream) {
    const float* x   = (const float*)d_in[0];
    const int*   adj = (const int*)d_in[1];
    const float* W   = (const float*)d_in[2];
    const float* b   = (const float*)d_in[3];
    const float* a   = (const float*)d_in[4];
    const float* a_b = (const float*)d_in[5];
    float* out = (float*)d_out;

    char* ws = (char*)d_ws;
    float2* EFi = (float2*)ws;                                   // 64 KB
    float2* EFd = (float2*)(ws + 64 * 1024);                     // 64 KB
    unsigned short* hswz = (unsigned short*)(ws + 128 * 1024);   // 1 MB
    unsigned long long* bitsW = (unsigned long long*)(ws + 128 * 1024 + 1024 * 1024); // 8 MB
    const unsigned int* bitsR = (const unsigned int*)bitsW;

    hipLaunchKernelGGL(gat_h, dim3(N_NODES / 16), dim3(512), 0, stream,
                       x, W, b, a, a_b, EFi, EFd, hswz);
    hipLaunchKernelGGL(adj_bits, dim3(N_NODES / 4), dim3(256), 0, stream, adj, bitsW);
    hipLaunchKernelGGL(gat_attn, dim3(N_NODES / 16), dim3(512), 0, stream,
                       bitsR, EFi, EFd, hswz, out);
}